// Round 1
// baseline (109.399 us; speedup 1.0000x reference)
//
#include <hip/hip_runtime.h>
#include <math.h>

// Sizes fixed by the reference
#define NB 2
#define NN 256
#define KD 16
#define VV 32000
#define EPS_SELF 1e-8f
#define EPS_AL   1e-6f
#define NNODES (NB*NN)   // 512

// ws layout (float offsets)
#define OFF_MT  0                       // 512*16  rotated means
#define OFF_SH  (NNODES*16)             // 512*256 Shat = E^T Sigma E + eps I
#define OFF_P   (OFF_SH + NNODES*256)   // 512*256 P = (Shat)^-1
#define OFF_LD  (OFF_P + NNODES*256)    // 512     2*sum log(diag(cholO)+eps)
#define OFF_KLS (OFF_LD + NNODES)       // 512     per-node kl_self
#define OFF_CE  (OFF_KLS + NNODES)      // 512     per-row cross entropy
#define OFF_AP  (OFF_CE + NNODES)       // 512     align tile partials
#define WS_FLOATS (OFF_AP + NNODES)

__device__ inline float blockReduceSum256(float v, float* red) {
  #pragma unroll
  for (int o = 32; o; o >>= 1) v += __shfl_down(v, o);
  __syncthreads();
  if ((threadIdx.x & 63) == 0) red[threadIdx.x >> 6] = v;
  __syncthreads();
  float s = red[0] + red[1] + red[2] + red[3];
  __syncthreads();
  return s;
}

// In-place Cholesky (lower) of 16x16 SPD matrix in LDS. All 256 threads call.
__device__ inline void chol16(float* C, int tid, int r, int c) {
  for (int k = 0; k < 16; ++k) {
    if (tid == 0) C[k*17] = sqrtf(C[k*17]);
    __syncthreads();
    if (c == k && r > k) C[r*16+k] /= C[k*17];
    __syncthreads();
    if (r > k && c > k && c <= r) C[r*16+c] = fmaf(-C[r*16+k], C[c*16+k], C[r*16+c]);
    __syncthreads();
  }
}

__device__ inline float logdiag2(const float* C, float eps) {
  float s = 0.f;
  #pragma unroll
  for (int k = 0; k < 16; ++k) s += logf(C[k*17] + eps);
  return 2.f * s;
}

// LI = inv(L) for lower-triangular L stored in C (lower part). All threads call.
__device__ inline void linv16(const float* C, float* LI, int tid) {
  LI[tid] = 0.f;
  __syncthreads();
  if (tid < 16) {
    int cc = tid;
    for (int rr = cc; rr < 16; ++rr) {
      float v = (rr == cc) ? 1.f : 0.f;
      for (int j = cc; j < rr; ++j) v = fmaf(-C[rr*16+j], LI[j*16+cc], v);
      LI[rr*16+cc] = v / C[rr*17];
    }
  }
  __syncthreads();
}

// dst = A*B (16x16), internal syncs allow dst aliasing A or B
__device__ inline void mm16(float* dst, const float* A, const float* B, int r, int c, int tid) {
  float acc = 0.f;
  #pragma unroll
  for (int k = 0; k < 16; ++k) acc = fmaf(A[r*16+k], B[k*16+c], acc);
  __syncthreads();
  dst[tid] = acc;
  __syncthreads();
}

// ---------------- Kernel 1: per-node prep + V_self ----------------
__global__ __launch_bounds__(256) void prep_kernel(
    const float* __restrict__ mu, const float* __restrict__ Sigma,
    const float* __restrict__ phi, const float* __restrict__ mu_prior,
    const float* __restrict__ Sigma_prior, const float* __restrict__ gen,
    float* __restrict__ ws)
{
  __shared__ float bufA[256], bufT[256], bufU[256], bufS[256];
  __shared__ float phi_s[16], vec_s[16], red[4];
  const int tid = threadIdx.x;
  const int r = tid >> 4, c = tid & 15;
  const int node = blockIdx.x;

  if (tid < 16) phi_s[tid] = phi[node*16 + tid];
  bufS[tid] = Sigma[node*256 + tid];
  __syncthreads();

  // M = phi_mat / 16 (scaling for squaring), phi_mat = sum_a phi[a]*G[a]
  {
    float pm = 0.f;
    #pragma unroll
    for (int a = 0; a < 16; ++a) pm = fmaf(phi_s[a], gen[a*256 + tid], pm);
    bufA[tid] = pm * 0.0625f;
    bufT[tid] = (r == c) ? 1.f : 0.f;
  }
  __syncthreads();

  // Horner Taylor order 10: T = I + M*T/k
  for (int k = 10; k >= 1; --k) {
    float acc = 0.f;
    #pragma unroll
    for (int j = 0; j < 16; ++j) acc = fmaf(bufA[r*16+j], bufT[j*16+c], acc);
    __syncthreads();
    bufT[tid] = ((r == c) ? 1.f : 0.f) + acc / (float)k;
    __syncthreads();
  }
  // square 4x  -> E in bufT (orthogonal since phi_mat skew-symmetric)
  for (int s = 0; s < 4; ++s) {
    float acc = 0.f;
    #pragma unroll
    for (int j = 0; j < 16; ++j) acc = fmaf(bufT[r*16+j], bufT[j*16+c], acc);
    __syncthreads();
    bufT[tid] = acc;
    __syncthreads();
  }

  // U = Sigma * E
  mm16(bufU, bufS, bufT, r, c, tid);
  // Shat = E^T * U + eps*I  -> ws
  {
    float acc = 0.f;
    #pragma unroll
    for (int j = 0; j < 16; ++j) acc = fmaf(bufT[j*16+r], bufU[j*16+c], acc);
    ws[OFF_SH + node*256 + tid] = acc + ((r == c) ? EPS_AL : 0.f);
  }
  // m~ = E^T mu
  if (tid < 16) vec_s[tid] = mu[node*16 + tid];
  __syncthreads();
  if (tid < 16) {
    float acc = 0.f;
    #pragma unroll
    for (int rr = 0; rr < 16; ++rr) acc = fmaf(bufT[rr*16+tid], vec_s[rr], acc);
    ws[OFF_MT + node*16 + tid] = acc;
  }

  // cholO of (Sigma + eps_al I): logdet (with +eps inside log, matches ref)
  bufA[tid] = bufS[tid] + ((r == c) ? EPS_AL : 0.f);
  __syncthreads();
  chol16(bufA, tid, r, c);
  if (tid == 0) ws[OFF_LD + node] = logdiag2(bufA, EPS_AL);
  // Q = inv(Sigma + eps_al I) via LI
  linv16(bufA, bufU, tid);
  {
    float acc = 0.f;
    int m0 = (r > c) ? r : c;
    for (int k = m0; k < 16; ++k) acc = fmaf(bufU[k*16+r], bufU[k*16+c], acc);
    __syncthreads();
    bufA[tid] = acc;       // Q
    __syncthreads();
  }
  // P = E^T Q E  (= inv(Shat))
  mm16(bufU, bufA, bufT, r, c, tid);   // V1 = Q*E
  {
    float acc = 0.f;
    #pragma unroll
    for (int j = 0; j < 16; ++j) acc = fmaf(bufT[j*16+r], bufU[j*16+c], acc);
    ws[OFF_P + node*256 + tid] = acc;
  }

  // ---------------- V_self ----------------
  // logdet(Sq), Sq = Sigma + 1e-8 I   (exact slogdet -> no eps in log)
  __syncthreads();
  bufA[tid] = bufS[tid] + ((r == c) ? EPS_SELF : 0.f);
  __syncthreads();
  chol16(bufA, tid, r, c);
  float ldSq = logdiag2(bufA, 0.f);
  __syncthreads();
  // Sp = Sigma_prior + 1e-8 I -> bufT (E no longer needed)
  bufT[tid] = Sigma_prior[node*256 + tid];
  __syncthreads();
  bufA[tid] = bufT[tid] + ((r == c) ? EPS_SELF : 0.f);
  __syncthreads();
  chol16(bufA, tid, r, c);
  float ldSp = logdiag2(bufA, 0.f);
  __syncthreads();
  linv16(bufA, bufU, tid);
  {
    float acc = 0.f;
    int m0 = (r > c) ? r : c;
    for (int k = m0; k < 16; ++k) acc = fmaf(bufU[k*16+r], bufU[k*16+c], acc);
    __syncthreads();
    bufT[tid] = acc;       // Spinv
    __syncthreads();
  }
  if (tid < 16) vec_s[tid] = mu_prior[node*16 + tid] - mu[node*16 + tid];
  __syncthreads();
  // trace(Spinv*Sq) + dmu^T Spinv dmu in one reduction
  float sq = bufS[tid] + ((r == c) ? EPS_SELF : 0.f);
  float val = bufT[tid] * (sq + vec_s[r] * vec_s[c]);
  float tot = blockReduceSum256(val, red);
  if (tid == 0) ws[OFF_KLS + node] = 0.5f * (tot - 16.f + ldSp - ldSq);
}

// ---------------- Kernel 2: pairwise V_align ----------------
#define PSTR 257
__global__ __launch_bounds__(256) void align_kernel(
    const float* __restrict__ beta, const float* __restrict__ wsc, float* __restrict__ ws)
{
  __shared__ float ShI[16*PSTR], PJ[16*PSTR];
  __shared__ float mtI[256], mtJ[256], ldI[16], ldJ[16], red[4];
  const int tid = threadIdx.x;
  const int ti = tid & 15, tj = tid >> 4;
  const int bx = blockIdx.x, by = blockIdx.y, bz = blockIdx.z;
  const int nodeI0 = bz*256 + by*16, nodeJ0 = bz*256 + bx*16;

  for (int idx = tid; idx < 16*256; idx += 256) {
    int row = idx >> 8, col = idx & 255;
    ShI[row*PSTR + col] = wsc[OFF_SH + (nodeI0 + row)*256 + col];
    PJ [row*PSTR + col] = wsc[OFF_P  + (nodeJ0 + row)*256 + col];
  }
  mtI[tid] = wsc[OFF_MT + nodeI0*16 + tid];
  mtJ[tid] = wsc[OFF_MT + nodeJ0*16 + tid];
  if (tid < 16) { ldI[tid] = wsc[OFF_LD + nodeI0 + tid]; ldJ[tid] = wsc[OFF_LD + nodeJ0 + tid]; }
  __syncthreads();

  const float* si = &ShI[ti*PSTR];
  const float* pj = &PJ[tj*PSTR];
  float tr = 0.f;
  #pragma unroll 8
  for (int t = 0; t < 256; ++t) tr = fmaf(si[t], pj[t], tr);

  float d[16];
  #pragma unroll
  for (int k = 0; k < 16; ++k) d[k] = mtJ[tj*16+k] - mtI[ti*16+k];
  float mah = 0.f;
  #pragma unroll
  for (int k = 0; k < 16; ++k) {
    float acc = 0.f;
    #pragma unroll
    for (int l = 0; l < 16; ++l) acc = fmaf(pj[k*16+l], d[l], acc);
    mah = fmaf(d[k], acc, mah);
  }

  float kl = 0.5f * (tr + mah - 16.f + ldJ[tj] - ldI[ti]);
  kl = fmaxf(kl, 0.f);
  int gi = by*16 + ti, gj = bx*16 + tj;
  float contrib = (gi == gj) ? 0.f : kl * beta[bz*65536 + gi*256 + gj];
  float tot = blockReduceSum256(contrib, red);
  if (tid == 0) ws[OFF_AP + (bz*16 + by)*16 + bx] = tot;
}

// ---------------- Kernel 3: V_ce (2 rows per block, online logsumexp) ----------------
#define DOT16(q0,q1,q2,q3,A) \
  fmaf(q0.x,A[0],fmaf(q0.y,A[1],fmaf(q0.z,A[2],fmaf(q0.w,A[3], \
  fmaf(q1.x,A[4],fmaf(q1.y,A[5],fmaf(q1.z,A[6],fmaf(q1.w,A[7], \
  fmaf(q2.x,A[8],fmaf(q2.y,A[9],fmaf(q2.z,A[10],fmaf(q2.w,A[11], \
  fmaf(q3.x,A[12],fmaf(q3.y,A[13],fmaf(q3.z,A[14],q3.w*A[15])))))))))))))))

__global__ __launch_bounds__(256) void ce_kernel(
    const float* __restrict__ mu, const float* __restrict__ W,
    const int* __restrict__ targets, float* __restrict__ ws)
{
  __shared__ float ms[256], ss[256];
  __shared__ float mu_s[2][16];
  const int tid = threadIdx.x;
  const int g0 = blockIdx.x * 2;
  if (tid < 32) mu_s[tid >> 4][tid & 15] = mu[g0*16 + tid];
  __syncthreads();

  float A0[16], A1[16];
  #pragma unroll
  for (int k = 0; k < 16; ++k) { A0[k] = mu_s[0][k]; A1[k] = mu_s[1][k]; }

  const float4* W4 = (const float4*)W;
  float m0 = -1e30f, s0 = 0.f, m1 = -1e30f, s1 = 0.f;
  for (int v = tid; v < VV; v += 256) {
    float4 q0 = W4[v*4+0], q1 = W4[v*4+1], q2 = W4[v*4+2], q3 = W4[v*4+3];
    float l0 = DOT16(q0,q1,q2,q3,A0);
    float l1 = DOT16(q0,q1,q2,q3,A1);
    if (l0 > m0) { s0 = fmaf(s0, __expf(m0 - l0), 1.f); m0 = l0; } else s0 += __expf(l0 - m0);
    if (l1 > m1) { s1 = fmaf(s1, __expf(m1 - l1), 1.f); m1 = l1; } else s1 += __expf(l1 - m1);
  }

  // row 0 reduce
  ms[tid] = m0; ss[tid] = s0; __syncthreads();
  for (int h = 128; h > 0; h >>= 1) {
    if (tid < h) {
      float ma = ms[tid], sa = ss[tid], mb = ms[tid+h], sb = ss[tid+h];
      float M = fmaxf(ma, mb);
      ss[tid] = sa * __expf(ma - M) + sb * __expf(mb - M);
      ms[tid] = M;
    }
    __syncthreads();
  }
  if (tid == 0) {
    int t0 = targets[g0];
    float dt = 0.f;
    #pragma unroll
    for (int k = 0; k < 16; ++k) dt = fmaf(mu_s[0][k], W[t0*16+k], dt);
    ws[OFF_CE + g0] = ms[0] + logf(ss[0]) - dt;
  }
  __syncthreads();
  // row 1 reduce
  ms[tid] = m1; ss[tid] = s1; __syncthreads();
  for (int h = 128; h > 0; h >>= 1) {
    if (tid < h) {
      float ma = ms[tid], sa = ss[tid], mb = ms[tid+h], sb = ss[tid+h];
      float M = fmaxf(ma, mb);
      ss[tid] = sa * __expf(ma - M) + sb * __expf(mb - M);
      ms[tid] = M;
    }
    __syncthreads();
  }
  if (tid == 0) {
    int t1 = targets[g0+1];
    float dt = 0.f;
    #pragma unroll
    for (int k = 0; k < 16; ++k) dt = fmaf(mu_s[1][k], W[t1*16+k], dt);
    ws[OFF_CE + g0 + 1] = ms[0] + logf(ss[0]) - dt;
  }
}

// ---------------- Kernel 4: deterministic final reduce ----------------
__global__ void final_kernel(const float* __restrict__ ws, float* __restrict__ out) {
  int b = threadIdx.x;
  if (b < NB) {
    double acc = 0.0;
    for (int i = 0; i < 256; ++i) acc += (double)ws[OFF_KLS + b*256 + i];
    for (int i = 0; i < 256; ++i) acc += (double)ws[OFF_CE  + b*256 + i];
    for (int i = 0; i < 256; ++i) acc += (double)ws[OFF_AP  + b*256 + i];
    out[b] = (float)acc;
  }
}

extern "C" void kernel_launch(void* const* d_in, const int* in_sizes, int n_in,
                              void* d_out, int out_size, void* d_ws, size_t ws_size,
                              hipStream_t stream) {
  const float* mu          = (const float*)d_in[0];
  const float* Sigma       = (const float*)d_in[1];
  const float* phi         = (const float*)d_in[2];
  const float* mu_prior    = (const float*)d_in[3];
  const float* Sigma_prior = (const float*)d_in[4];
  const float* beta        = (const float*)d_in[5];
  const float* W_out       = (const float*)d_in[6];
  const float* gen         = (const float*)d_in[7];
  const int*   targets     = (const int*)d_in[8];
  float* out = (float*)d_out;
  float* ws  = (float*)d_ws;
  if (ws_size < (size_t)WS_FLOATS * sizeof(float)) return;  // fail loudly (out stays poisoned)

  prep_kernel<<<NNODES, 256, 0, stream>>>(mu, Sigma, phi, mu_prior, Sigma_prior, gen, ws);
  dim3 ag(16, 16, NB);
  align_kernel<<<ag, 256, 0, stream>>>(beta, ws, ws);
  ce_kernel<<<NNODES/2, 256, 0, stream>>>(mu, W_out, targets, ws);
  final_kernel<<<1, 64, 0, stream>>>(ws, out);
}

// Round 2
// 73.336 us; speedup vs baseline: 1.4918x; 1.4918x over previous
//
#include <hip/hip_runtime.h>
#include <math.h>

// Sizes fixed by the reference
#define NB 2
#define NN 256
#define KD 16
#define VV 32000
#define EPS_SELF 1e-8f
#define EPS_AL   1e-6f
#define NNODES (NB*NN)   // 512

#define CE_ROWS 8
#define CE_CH   32
#define CE_CHUNK (VV/CE_CH)   // 1000

// ws layout (float offsets)
#define OFF_MT  0                       // 512*16  rotated means
#define OFF_SH  (NNODES*16)             // 512*256 Shat = E^T Sigma E + eps I
#define OFF_P   (OFF_SH + NNODES*256)   // 512*256 P = (Shat)^-1
#define OFF_LD  (OFF_P + NNODES*256)    // 512     2*sum log(diag(cholO)+eps)
#define OFF_KLS (OFF_LD + NNODES)       // 512     per-node kl_self
#define OFF_CE  (OFF_KLS + NNODES)      // 512     per-row cross entropy
#define OFF_AP  (OFF_CE + NNODES)       // 512     align tile partials
#define OFF_CEP (OFF_AP + NNODES)       // 512*32  ce chunk partial sums
#define WS_FLOATS (OFF_CEP + NNODES*CE_CH)

__device__ inline float blockReduceSum256(float v, float* red) {
  #pragma unroll
  for (int o = 32; o; o >>= 1) v += __shfl_down(v, o);
  __syncthreads();
  if ((threadIdx.x & 63) == 0) red[threadIdx.x >> 6] = v;
  __syncthreads();
  float s = red[0] + red[1] + red[2] + red[3];
  __syncthreads();
  return s;
}

// In-place Cholesky (lower) of 16x16 SPD matrix in LDS. All 256 threads call.
__device__ inline void chol16(float* C, int tid, int r, int c) {
  for (int k = 0; k < 16; ++k) {
    if (tid == 0) C[k*17] = sqrtf(C[k*17]);
    __syncthreads();
    if (c == k && r > k) C[r*16+k] /= C[k*17];
    __syncthreads();
    if (r > k && c > k && c <= r) C[r*16+c] = fmaf(-C[r*16+k], C[c*16+k], C[r*16+c]);
    __syncthreads();
  }
}

__device__ inline float logdiag2(const float* C, float eps) {
  float s = 0.f;
  #pragma unroll
  for (int k = 0; k < 16; ++k) s += logf(C[k*17] + eps);
  return 2.f * s;
}

// LI = inv(L) for lower-triangular L stored in C (lower part). All threads call.
__device__ inline void linv16(const float* C, float* LI, int tid) {
  LI[tid] = 0.f;
  __syncthreads();
  if (tid < 16) {
    int cc = tid;
    for (int rr = cc; rr < 16; ++rr) {
      float v = (rr == cc) ? 1.f : 0.f;
      for (int j = cc; j < rr; ++j) v = fmaf(-C[rr*16+j], LI[j*16+cc], v);
      LI[rr*16+cc] = v / C[rr*17];
    }
  }
  __syncthreads();
}

// dst = A*B (16x16), internal syncs allow dst aliasing A or B
__device__ inline void mm16(float* dst, const float* A, const float* B, int r, int c, int tid) {
  float acc = 0.f;
  #pragma unroll
  for (int k = 0; k < 16; ++k) acc = fmaf(A[r*16+k], B[k*16+c], acc);
  __syncthreads();
  dst[tid] = acc;
  __syncthreads();
}

// ---------------- Kernel 1: per-node prep + V_self ----------------
__global__ __launch_bounds__(256) void prep_kernel(
    const float* __restrict__ mu, const float* __restrict__ Sigma,
    const float* __restrict__ phi, const float* __restrict__ mu_prior,
    const float* __restrict__ Sigma_prior, const float* __restrict__ gen,
    float* __restrict__ ws)
{
  __shared__ float bufA[256], bufT[256], bufU[256], bufS[256];
  __shared__ float phi_s[16], vec_s[16], red[4];
  const int tid = threadIdx.x;
  const int r = tid >> 4, c = tid & 15;
  const int node = blockIdx.x;

  if (tid < 16) phi_s[tid] = phi[node*16 + tid];
  bufS[tid] = Sigma[node*256 + tid];
  __syncthreads();

  // M = phi_mat / 16 (scaling for squaring), phi_mat = sum_a phi[a]*G[a]
  {
    float pm = 0.f;
    #pragma unroll
    for (int a = 0; a < 16; ++a) pm = fmaf(phi_s[a], gen[a*256 + tid], pm);
    bufA[tid] = pm * 0.0625f;
    bufT[tid] = (r == c) ? 1.f : 0.f;
  }
  __syncthreads();

  // Horner Taylor order 10: T = I + M*T/k
  for (int k = 10; k >= 1; --k) {
    float acc = 0.f;
    #pragma unroll
    for (int j = 0; j < 16; ++j) acc = fmaf(bufA[r*16+j], bufT[j*16+c], acc);
    __syncthreads();
    bufT[tid] = ((r == c) ? 1.f : 0.f) + acc / (float)k;
    __syncthreads();
  }
  // square 4x  -> E in bufT (orthogonal since phi_mat skew-symmetric)
  for (int s = 0; s < 4; ++s) {
    float acc = 0.f;
    #pragma unroll
    for (int j = 0; j < 16; ++j) acc = fmaf(bufT[r*16+j], bufT[j*16+c], acc);
    __syncthreads();
    bufT[tid] = acc;
    __syncthreads();
  }

  // U = Sigma * E
  mm16(bufU, bufS, bufT, r, c, tid);
  // Shat = E^T * U + eps*I  -> ws
  {
    float acc = 0.f;
    #pragma unroll
    for (int j = 0; j < 16; ++j) acc = fmaf(bufT[j*16+r], bufU[j*16+c], acc);
    ws[OFF_SH + node*256 + tid] = acc + ((r == c) ? EPS_AL : 0.f);
  }
  // m~ = E^T mu
  if (tid < 16) vec_s[tid] = mu[node*16 + tid];
  __syncthreads();
  if (tid < 16) {
    float acc = 0.f;
    #pragma unroll
    for (int rr = 0; rr < 16; ++rr) acc = fmaf(bufT[rr*16+tid], vec_s[rr], acc);
    ws[OFF_MT + node*16 + tid] = acc;
  }

  // cholO of (Sigma + eps_al I): logdet (with +eps inside log, matches ref)
  bufA[tid] = bufS[tid] + ((r == c) ? EPS_AL : 0.f);
  __syncthreads();
  chol16(bufA, tid, r, c);
  if (tid == 0) ws[OFF_LD + node] = logdiag2(bufA, EPS_AL);
  // Q = inv(Sigma + eps_al I) via LI
  linv16(bufA, bufU, tid);
  {
    float acc = 0.f;
    int m0 = (r > c) ? r : c;
    for (int k = m0; k < 16; ++k) acc = fmaf(bufU[k*16+r], bufU[k*16+c], acc);
    __syncthreads();
    bufA[tid] = acc;       // Q
    __syncthreads();
  }
  // P = E^T Q E  (= inv(Shat))
  mm16(bufU, bufA, bufT, r, c, tid);   // V1 = Q*E
  {
    float acc = 0.f;
    #pragma unroll
    for (int j = 0; j < 16; ++j) acc = fmaf(bufT[j*16+r], bufU[j*16+c], acc);
    ws[OFF_P + node*256 + tid] = acc;
  }

  // ---------------- V_self ----------------
  __syncthreads();
  bufA[tid] = bufS[tid] + ((r == c) ? EPS_SELF : 0.f);
  __syncthreads();
  chol16(bufA, tid, r, c);
  float ldSq = logdiag2(bufA, 0.f);
  __syncthreads();
  bufT[tid] = Sigma_prior[node*256 + tid];
  __syncthreads();
  bufA[tid] = bufT[tid] + ((r == c) ? EPS_SELF : 0.f);
  __syncthreads();
  chol16(bufA, tid, r, c);
  float ldSp = logdiag2(bufA, 0.f);
  __syncthreads();
  linv16(bufA, bufU, tid);
  {
    float acc = 0.f;
    int m0 = (r > c) ? r : c;
    for (int k = m0; k < 16; ++k) acc = fmaf(bufU[k*16+r], bufU[k*16+c], acc);
    __syncthreads();
    bufT[tid] = acc;       // Spinv
    __syncthreads();
  }
  if (tid < 16) vec_s[tid] = mu_prior[node*16 + tid] - mu[node*16 + tid];
  __syncthreads();
  float sq = bufS[tid] + ((r == c) ? EPS_SELF : 0.f);
  float val = bufT[tid] * (sq + vec_s[r] * vec_s[c]);
  float tot = blockReduceSum256(val, red);
  if (tid == 0) ws[OFF_KLS + node] = 0.5f * (tot - 16.f + ldSp - ldSq);
}

// ---------------- Kernel 2: pairwise V_align ----------------
#define PSTR 257
__global__ __launch_bounds__(256) void align_kernel(
    const float* __restrict__ beta, const float* __restrict__ wsc, float* __restrict__ ws)
{
  __shared__ float ShI[16*PSTR], PJ[16*PSTR];
  __shared__ float mtI[256], mtJ[256], ldI[16], ldJ[16], red[4];
  const int tid = threadIdx.x;
  const int ti = tid & 15, tj = tid >> 4;
  const int bx = blockIdx.x, by = blockIdx.y, bz = blockIdx.z;
  const int nodeI0 = bz*256 + by*16, nodeJ0 = bz*256 + bx*16;

  for (int idx = tid; idx < 16*256; idx += 256) {
    int row = idx >> 8, col = idx & 255;
    ShI[row*PSTR + col] = wsc[OFF_SH + (nodeI0 + row)*256 + col];
    PJ [row*PSTR + col] = wsc[OFF_P  + (nodeJ0 + row)*256 + col];
  }
  mtI[tid] = wsc[OFF_MT + nodeI0*16 + tid];
  mtJ[tid] = wsc[OFF_MT + nodeJ0*16 + tid];
  if (tid < 16) { ldI[tid] = wsc[OFF_LD + nodeI0 + tid]; ldJ[tid] = wsc[OFF_LD + nodeJ0 + tid]; }
  __syncthreads();

  const float* si = &ShI[ti*PSTR];
  const float* pj = &PJ[tj*PSTR];
  float tr = 0.f;
  #pragma unroll 8
  for (int t = 0; t < 256; ++t) tr = fmaf(si[t], pj[t], tr);

  float d[16];
  #pragma unroll
  for (int k = 0; k < 16; ++k) d[k] = mtJ[tj*16+k] - mtI[ti*16+k];
  float mah = 0.f;
  #pragma unroll
  for (int k = 0; k < 16; ++k) {
    float acc = 0.f;
    #pragma unroll
    for (int l = 0; l < 16; ++l) acc = fmaf(pj[k*16+l], d[l], acc);
    mah = fmaf(d[k], acc, mah);
  }

  float kl = 0.5f * (tr + mah - 16.f + ldJ[tj] - ldI[ti]);
  kl = fmaxf(kl, 0.f);
  int gi = by*16 + ti, gj = bx*16 + tj;
  float contrib = (gi == gj) ? 0.f : kl * beta[bz*65536 + gi*256 + gj];
  float tot = blockReduceSum256(contrib, red);
  if (tid == 0) ws[OFF_AP + (bz*16 + by)*16 + bx] = tot;
}

// ---------------- Kernel 3a: CE partial sums (8 rows x 1000-vocab chunk per block) ----------------
#define DOT16(q0,q1,q2,q3,A) \
  fmaf(q0.x,A[0],fmaf(q0.y,A[1],fmaf(q0.z,A[2],fmaf(q0.w,A[3], \
  fmaf(q1.x,A[4],fmaf(q1.y,A[5],fmaf(q1.z,A[6],fmaf(q1.w,A[7], \
  fmaf(q2.x,A[8],fmaf(q2.y,A[9],fmaf(q2.z,A[10],fmaf(q2.w,A[11], \
  fmaf(q3.x,A[12],fmaf(q3.y,A[13],fmaf(q3.z,A[14],q3.w*A[15])))))))))))))))

__global__ __launch_bounds__(256) void ce1_kernel(
    const float* __restrict__ mu, const float* __restrict__ W,
    float* __restrict__ ws)
{
  __shared__ float mu_s[CE_ROWS*16];
  __shared__ float sred[CE_ROWS*256];   // 8 KB
  const int tid = threadIdx.x;
  const int grp = blockIdx.x;           // 0..63  (row group)
  const int ch  = blockIdx.y;           // 0..31  (vocab chunk)
  const int row0 = grp * CE_ROWS;

  if (tid < CE_ROWS*16) mu_s[tid] = mu[row0*16 + tid];
  __syncthreads();

  float A[CE_ROWS][16];
  #pragma unroll
  for (int r = 0; r < CE_ROWS; ++r)
    #pragma unroll
    for (int k = 0; k < 16; ++k) A[r][k] = mu_s[r*16+k];

  float acc[CE_ROWS];
  #pragma unroll
  for (int r = 0; r < CE_ROWS; ++r) acc[r] = 0.f;

  const float4* W4 = (const float4*)W;
  const int v0 = ch * CE_CHUNK;
  for (int v = v0 + tid; v < v0 + CE_CHUNK; v += 256) {
    float4 q0 = W4[v*4+0], q1 = W4[v*4+1], q2 = W4[v*4+2], q3 = W4[v*4+3];
    #pragma unroll
    for (int r = 0; r < CE_ROWS; ++r) {
      float l = DOT16(q0,q1,q2,q3,A[r]);
      acc[r] += __expf(l);   // logits are O(0.4): direct exp-sum is fp32-safe
    }
  }

  #pragma unroll
  for (int r = 0; r < CE_ROWS; ++r) sred[r*256 + tid] = acc[r];
  __syncthreads();
  for (int h = 128; h > 0; h >>= 1) {
    if (tid < h) {
      #pragma unroll
      for (int r = 0; r < CE_ROWS; ++r) sred[r*256+tid] += sred[r*256+tid+h];
    }
    __syncthreads();
  }
  if (tid < CE_ROWS) ws[OFF_CEP + (row0 + tid)*CE_CH + ch] = sred[tid*256];
}

// ---------------- Kernel 3b: CE finalize (one row per thread) ----------------
__global__ __launch_bounds__(256) void ce2_kernel(
    const float* __restrict__ mu, const float* __restrict__ W,
    const int* __restrict__ targets, float* __restrict__ ws)
{
  int row = blockIdx.x*256 + threadIdx.x;
  if (row < NNODES) {
    float s = 0.f;
    #pragma unroll
    for (int c = 0; c < CE_CH; ++c) s += ws[OFF_CEP + row*CE_CH + c];
    int t = targets[row];
    float dt = 0.f;
    #pragma unroll
    for (int k = 0; k < 16; ++k) dt = fmaf(mu[row*16+k], W[t*16+k], dt);
    ws[OFF_CE + row] = logf(s) - dt;
  }
}

// ---------------- Kernel 4: deterministic final reduce ----------------
__global__ __launch_bounds__(256) void final_kernel(const float* __restrict__ ws, float* __restrict__ out) {
  __shared__ double red[256];
  const int tid = threadIdx.x;
  const int b = tid >> 7, t = tid & 127;   // 128 threads per batch
  double acc = 0.0;
  for (int i = t; i < 256; i += 128) {
    acc += (double)ws[OFF_KLS + b*256 + i];
    acc += (double)ws[OFF_CE  + b*256 + i];
    acc += (double)ws[OFF_AP  + b*256 + i];
  }
  red[tid] = acc;
  __syncthreads();
  for (int h = 64; h > 0; h >>= 1) {
    if (t < h) red[tid] += red[tid + h];
    __syncthreads();
  }
  if (t == 0) out[b] = (float)red[tid];
}

extern "C" void kernel_launch(void* const* d_in, const int* in_sizes, int n_in,
                              void* d_out, int out_size, void* d_ws, size_t ws_size,
                              hipStream_t stream) {
  const float* mu          = (const float*)d_in[0];
  const float* Sigma       = (const float*)d_in[1];
  const float* phi         = (const float*)d_in[2];
  const float* mu_prior    = (const float*)d_in[3];
  const float* Sigma_prior = (const float*)d_in[4];
  const float* beta        = (const float*)d_in[5];
  const float* W_out       = (const float*)d_in[6];
  const float* gen         = (const float*)d_in[7];
  const int*   targets     = (const int*)d_in[8];
  float* out = (float*)d_out;
  float* ws  = (float*)d_ws;
  if (ws_size < (size_t)WS_FLOATS * sizeof(float)) return;  // fail loudly (out stays poisoned)

  prep_kernel<<<NNODES, 256, 0, stream>>>(mu, Sigma, phi, mu_prior, Sigma_prior, gen, ws);
  dim3 ag(16, 16, NB);
  align_kernel<<<ag, 256, 0, stream>>>(beta, ws, ws);
  dim3 cg(NNODES/CE_ROWS, CE_CH);
  ce1_kernel<<<cg, 256, 0, stream>>>(mu, W_out, ws);
  ce2_kernel<<<(NNODES+255)/256, 256, 0, stream>>>(mu, W_out, targets, ws);
  final_kernel<<<1, 256, 0, stream>>>(ws, out);
}

// Round 3
// 54.111 us; speedup vs baseline: 2.0218x; 1.3553x over previous
//
#include <hip/hip_runtime.h>
#include <math.h>

// Sizes fixed by the reference
#define NB 2
#define NN 256
#define KD 16
#define VV 32000
#define EPS_SELF 1e-8f
#define EPS_AL   1e-6f
#define NNODES (NB*NN)   // 512

#define CE_ROWS 8
#define CE_CH   32
#define CE_CHUNK (VV/CE_CH)   // 1000

// ws layout (float offsets)
#define OFF_MT  0                       // 512*16  rotated means
#define OFF_SH  (NNODES*16)             // 512*256 Shat = E^T Sigma E + eps I
#define OFF_P   (OFF_SH + NNODES*256)   // 512*256 P = (Shat)^-1
#define OFF_LD  (OFF_P + NNODES*256)    // 512     2*sum log(sqrt(d_k)+eps)
#define OFF_KLS (OFF_LD + NNODES)       // 512     per-node kl_self
#define OFF_CE  (OFF_KLS + NNODES)      // 512     (unused now)
#define OFF_AP  (OFF_CE + NNODES)       // 512     align tile partials
#define OFF_CEP (OFF_AP + NNODES)       // 512*32  ce chunk partial sums
#define WS_FLOATS (OFF_CEP + NNODES*CE_CH)

__device__ inline float blockReduceSum256(float v, float* red) {
  #pragma unroll
  for (int o = 32; o; o >>= 1) v += __shfl_down(v, o);
  __syncthreads();
  if ((threadIdx.x & 63) == 0) red[threadIdx.x >> 6] = v;
  __syncthreads();
  float s = red[0] + red[1] + red[2] + red[3];
  __syncthreads();
  return s;
}

// ---------------- Kernel 1: per-node prep (role 0) + V_self (role 1) ----------------
// role 0: E=expm(phi_mat); Shat=E^T Sigma E + eps; mt=E^T mu; P=inv(Shat) via GJ
// role 1: GJ(Sp)->Spinv+ldSp; elim(Sq)->ldSq; elim(Sg)->ld(align quirk); kl_self
__global__ __launch_bounds__(256) void prep_kernel(
    const float* __restrict__ mu, const float* __restrict__ Sigma,
    const float* __restrict__ phi, const float* __restrict__ mu_prior,
    const float* __restrict__ Sigma_prior, const float* __restrict__ gen,
    float* __restrict__ ws)
{
  __shared__ float bufA[256], bufT[256], bufU[256], bufS[256];
  __shared__ float srow[16], scol[16], vec_s[16], phi_s[16], red[4];
  const int tid = threadIdx.x;
  const int r = tid >> 4, c = tid & 15;
  const int bid = blockIdx.x;
  const int role = bid & 1, node = bid >> 1;

  if (role == 0) {
    // ---------- expm + Shat + mt + P ----------
    if (tid < 16) phi_s[tid] = phi[node*16 + tid];
    bufS[tid] = Sigma[node*256 + tid];
    __syncthreads();
    // X = phi_mat / 8
    float pm = 0.f;
    #pragma unroll
    for (int a = 0; a < 16; ++a) pm = fmaf(phi_s[a], gen[a*256 + tid], pm);
    bufA[tid] = pm * 0.125f;
    __syncthreads();
    float Mrow[16];
    #pragma unroll
    for (int j = 0; j < 16; ++j) Mrow[j] = bufA[r*16 + j];
    // Horner Taylor order 8: P8 = I + X/8; then P = I + X*P/k, k=7..1
    bufT[tid] = ((r == c) ? 1.f : 0.f) + bufA[tid] * 0.125f;
    __syncthreads();
    for (int k = 7; k >= 1; --k) {
      float acc = 0.f;
      #pragma unroll
      for (int j = 0; j < 16; ++j) acc = fmaf(Mrow[j], bufT[j*16 + c], acc);
      __syncthreads();
      bufT[tid] = ((r == c) ? 1.f : 0.f) + acc / (float)k;
      __syncthreads();
    }
    // 3 squarings -> E in bufT (orthogonal since phi_mat skew-symmetric)
    for (int s = 0; s < 3; ++s) {
      float acc = 0.f;
      #pragma unroll
      for (int j = 0; j < 16; ++j) acc = fmaf(bufT[r*16 + j], bufT[j*16 + c], acc);
      __syncthreads();
      bufT[tid] = acc;
      __syncthreads();
    }
    // U = Sigma * E
    {
      float acc = 0.f;
      #pragma unroll
      for (int j = 0; j < 16; ++j) acc = fmaf(bufS[r*16 + j], bufT[j*16 + c], acc);
      bufU[tid] = acc;
    }
    __syncthreads();
    // Shat = E^T U + eps I
    {
      float sh = 0.f;
      #pragma unroll
      for (int j = 0; j < 16; ++j) sh = fmaf(bufT[j*16 + r], bufU[j*16 + c], sh);
      sh += (r == c) ? EPS_AL : 0.f;
      ws[OFF_SH + node*256 + tid] = sh;
      bufA[tid] = sh;
    }
    if (tid < 16) vec_s[tid] = mu[node*16 + tid];
    __syncthreads();
    if (tid < 16) {
      float acc = 0.f;
      #pragma unroll
      for (int rr = 0; rr < 16; ++rr) acc = fmaf(bufT[rr*16 + tid], vec_s[rr], acc);
      ws[OFF_MT + node*16 + tid] = acc;
    }
    // Gauss-Jordan: bufA -> inv(bufA).  Cross-thread comms only via srow/scol.
    for (int k = 0; k < 16; ++k) {
      if (r == k) srow[c] = bufA[k*16 + c];
      if (c == k) scol[r] = bufA[r*16 + k];
      __syncthreads();
      float d = srow[k], dinv = 1.f / d;
      float v;
      if (r == k)      v = (c == k) ? dinv : srow[c] * dinv;
      else if (c == k) v = -scol[r] * dinv;
      else             v = fmaf(-scol[r] * dinv, srow[c], bufA[tid]);
      bufA[tid] = v;
      __syncthreads();
    }
    ws[OFF_P + node*256 + tid] = bufA[tid];
  } else {
    // ---------- V_self + align logdet ----------
    bufS[tid] = Sigma[node*256 + tid];
    bufA[tid] = Sigma_prior[node*256 + tid] + ((r == c) ? EPS_SELF : 0.f);
    if (tid < 16) vec_s[tid] = mu_prior[node*16 + tid] - mu[node*16 + tid];
    __syncthreads();
    // GJ(Sp) -> Spinv, ldSp = sum log d_k
    float ldSp = 0.f;
    for (int k = 0; k < 16; ++k) {
      if (r == k) srow[c] = bufA[k*16 + c];
      if (c == k) scol[r] = bufA[r*16 + k];
      __syncthreads();
      float d = srow[k], dinv = 1.f / d;
      ldSp += logf(d);
      float v;
      if (r == k)      v = (c == k) ? dinv : srow[c] * dinv;
      else if (c == k) v = -scol[r] * dinv;
      else             v = fmaf(-scol[r] * dinv, srow[c], bufA[tid]);
      bufA[tid] = v;
      __syncthreads();
    }
    // trace(Spinv*Sq) + dmu^T Spinv dmu
    float sq = bufS[tid] + ((r == c) ? EPS_SELF : 0.f);
    float val = bufA[tid] * (sq + vec_s[r] * vec_s[c]);
    float tot = blockReduceSum256(val, red);
    // ldSq via elimination (1 barrier/step; cross reads hit frozen row/col k only)
    bufU[tid] = bufS[tid] + ((r == c) ? EPS_SELF : 0.f);
    __syncthreads();
    float ldSq = 0.f;
    for (int k = 0; k < 16; ++k) {
      float d = bufU[k*17];
      ldSq += logf(d);
      if (r > k && c > k) {
        float dinv = 1.f / d;
        bufU[tid] = fmaf(-bufU[r*16 + k] * dinv, bufU[k*16 + c], bufU[tid]);
      }
      __syncthreads();
    }
    // align logdet quirk: 2*sum log(sqrt(d_k)+eps) over pivots of Sigma+1e-6 I
    bufU[tid] = bufS[tid] + ((r == c) ? EPS_AL : 0.f);
    __syncthreads();
    float ldq = 0.f;
    for (int k = 0; k < 16; ++k) {
      float d = bufU[k*17];
      ldq += 2.f * logf(sqrtf(d) + EPS_AL);
      if (r > k && c > k) {
        float dinv = 1.f / d;
        bufU[tid] = fmaf(-bufU[r*16 + k] * dinv, bufU[k*16 + c], bufU[tid]);
      }
      __syncthreads();
    }
    if (tid == 0) {
      ws[OFF_KLS + node] = 0.5f * (tot - 16.f + ldSp - ldSq);
      ws[OFF_LD + node] = ldq;
    }
  }
}

// ---------------- Kernel 2: pairwise V_align ----------------
#define PSTR 257
__global__ __launch_bounds__(256) void align_kernel(
    const float* __restrict__ beta, const float* __restrict__ wsc, float* __restrict__ ws)
{
  __shared__ float ShI[16*PSTR], PJ[16*PSTR];
  __shared__ float mtI[256], mtJ[256], ldI[16], ldJ[16], red[4];
  const int tid = threadIdx.x;
  const int ti = tid & 15, tj = tid >> 4;
  const int bx = blockIdx.x, by = blockIdx.y, bz = blockIdx.z;
  const int nodeI0 = bz*256 + by*16, nodeJ0 = bz*256 + bx*16;

  for (int idx = tid; idx < 16*256; idx += 256) {
    int row = idx >> 8, col = idx & 255;
    ShI[row*PSTR + col] = wsc[OFF_SH + (nodeI0 + row)*256 + col];
    PJ [row*PSTR + col] = wsc[OFF_P  + (nodeJ0 + row)*256 + col];
  }
  mtI[tid] = wsc[OFF_MT + nodeI0*16 + tid];
  mtJ[tid] = wsc[OFF_MT + nodeJ0*16 + tid];
  if (tid < 16) { ldI[tid] = wsc[OFF_LD + nodeI0 + tid]; ldJ[tid] = wsc[OFF_LD + nodeJ0 + tid]; }
  __syncthreads();

  const float* si = &ShI[ti*PSTR];
  const float* pj = &PJ[tj*PSTR];
  float tr = 0.f;
  #pragma unroll 8
  for (int t = 0; t < 256; ++t) tr = fmaf(si[t], pj[t], tr);

  float d[16];
  #pragma unroll
  for (int k = 0; k < 16; ++k) d[k] = mtJ[tj*16+k] - mtI[ti*16+k];
  float mah = 0.f;
  #pragma unroll
  for (int k = 0; k < 16; ++k) {
    float acc = 0.f;
    #pragma unroll
    for (int l = 0; l < 16; ++l) acc = fmaf(pj[k*16+l], d[l], acc);
    mah = fmaf(d[k], acc, mah);
  }

  float kl = 0.5f * (tr + mah - 16.f + ldJ[tj] - ldI[ti]);
  kl = fmaxf(kl, 0.f);
  int gi = by*16 + ti, gj = bx*16 + tj;
  float contrib = (gi == gj) ? 0.f : kl * beta[bz*65536 + gi*256 + gj];
  float tot = blockReduceSum256(contrib, red);
  if (tid == 0) ws[OFF_AP + (bz*16 + by)*16 + bx] = tot;
}

// ---------------- Kernel 3: CE partial sums (8 rows x 1000-vocab chunk per block) ----------------
#define DOT16(q0,q1,q2,q3,A) \
  fmaf(q0.x,A[0],fmaf(q0.y,A[1],fmaf(q0.z,A[2],fmaf(q0.w,A[3], \
  fmaf(q1.x,A[4],fmaf(q1.y,A[5],fmaf(q1.z,A[6],fmaf(q1.w,A[7], \
  fmaf(q2.x,A[8],fmaf(q2.y,A[9],fmaf(q2.z,A[10],fmaf(q2.w,A[11], \
  fmaf(q3.x,A[12],fmaf(q3.y,A[13],fmaf(q3.z,A[14],q3.w*A[15])))))))))))))))

__global__ __launch_bounds__(256) void ce1_kernel(
    const float* __restrict__ mu, const float* __restrict__ W,
    float* __restrict__ ws)
{
  __shared__ float mu_s[CE_ROWS*16];
  __shared__ float sred[CE_ROWS*256];   // 8 KB
  const int tid = threadIdx.x;
  const int grp = blockIdx.x;           // 0..63  (row group)
  const int ch  = blockIdx.y;           // 0..31  (vocab chunk)
  const int row0 = grp * CE_ROWS;

  if (tid < CE_ROWS*16) mu_s[tid] = mu[row0*16 + tid];
  __syncthreads();

  float A[CE_ROWS][16];
  #pragma unroll
  for (int r = 0; r < CE_ROWS; ++r)
    #pragma unroll
    for (int k = 0; k < 16; ++k) A[r][k] = mu_s[r*16+k];

  float acc[CE_ROWS];
  #pragma unroll
  for (int r = 0; r < CE_ROWS; ++r) acc[r] = 0.f;

  const float4* W4 = (const float4*)W;
  const int v0 = ch * CE_CHUNK;
  for (int v = v0 + tid; v < v0 + CE_CHUNK; v += 256) {
    float4 q0 = W4[v*4+0], q1 = W4[v*4+1], q2 = W4[v*4+2], q3 = W4[v*4+3];
    #pragma unroll
    for (int r = 0; r < CE_ROWS; ++r) {
      float l = DOT16(q0,q1,q2,q3,A[r]);
      acc[r] += __expf(l);   // logits are O(0.4): direct exp-sum is fp32-safe
    }
  }

  #pragma unroll
  for (int r = 0; r < CE_ROWS; ++r) sred[r*256 + tid] = acc[r];
  __syncthreads();
  for (int h = 128; h > 0; h >>= 1) {
    if (tid < h) {
      #pragma unroll
      for (int r = 0; r < CE_ROWS; ++r) sred[r*256+tid] += sred[r*256+tid+h];
    }
    __syncthreads();
  }
  if (tid < CE_ROWS) ws[OFF_CEP + (row0 + tid)*CE_CH + ch] = sred[tid*256];
}

// ---------------- Kernel 4: CE finalize + deterministic final reduce ----------------
__global__ __launch_bounds__(256) void final_kernel(
    const float* __restrict__ mu, const float* __restrict__ W,
    const int* __restrict__ targets, const float* __restrict__ ws,
    float* __restrict__ out)
{
  __shared__ double red[256];
  const int tid = threadIdx.x;
  double v[2];
  #pragma unroll
  for (int b = 0; b < 2; ++b) {
    int row = b*256 + tid;
    float s = 0.f;
    #pragma unroll
    for (int c2 = 0; c2 < CE_CH; ++c2) s += ws[OFF_CEP + row*CE_CH + c2];
    int t = targets[row];
    float dt = 0.f;
    #pragma unroll
    for (int k = 0; k < 16; ++k) dt = fmaf(mu[row*16+k], W[t*16+k], dt);
    double ce = (double)logf(s) - (double)dt;
    v[b] = (double)ws[OFF_KLS + row] + (double)ws[OFF_AP + row] + ce;
  }
  for (int b = 0; b < 2; ++b) {
    red[tid] = v[b];
    __syncthreads();
    for (int h = 128; h > 0; h >>= 1) {
      if (tid < h) red[tid] += red[tid + h];
      __syncthreads();
    }
    if (tid == 0) out[b] = (float)red[0];
    __syncthreads();
  }
}

extern "C" void kernel_launch(void* const* d_in, const int* in_sizes, int n_in,
                              void* d_out, int out_size, void* d_ws, size_t ws_size,
                              hipStream_t stream) {
  const float* mu          = (const float*)d_in[0];
  const float* Sigma       = (const float*)d_in[1];
  const float* phi         = (const float*)d_in[2];
  const float* mu_prior    = (const float*)d_in[3];
  const float* Sigma_prior = (const float*)d_in[4];
  const float* beta        = (const float*)d_in[5];
  const float* W_out       = (const float*)d_in[6];
  const float* gen         = (const float*)d_in[7];
  const int*   targets     = (const int*)d_in[8];
  float* out = (float*)d_out;
  float* ws  = (float*)d_ws;
  if (ws_size < (size_t)WS_FLOATS * sizeof(float)) return;  // fail loudly (out stays poisoned)

  prep_kernel<<<2*NNODES, 256, 0, stream>>>(mu, Sigma, phi, mu_prior, Sigma_prior, gen, ws);
  dim3 ag(16, 16, NB);
  align_kernel<<<ag, 256, 0, stream>>>(beta, ws, ws);
  dim3 cg(NNODES/CE_ROWS, CE_CH);
  ce1_kernel<<<cg, 256, 0, stream>>>(mu, W_out, ws);
  final_kernel<<<1, 256, 0, stream>>>(mu, W_out, targets, ws, out);
}

// Round 4
// 43.363 us; speedup vs baseline: 2.5229x; 1.2479x over previous
//
#include <hip/hip_runtime.h>
#include <math.h>

// Sizes fixed by the reference
#define NB 2
#define NN 256
#define KD 16
#define VV 32000
#define EPS_SELF 1e-8f
#define EPS_AL   1e-6f
#define NNODES (NB*NN)   // 512

#define CE_ROWS 8
#define CE_CH   32
#define CE_CHUNK (VV/CE_CH)   // 1000

// ws layout (float offsets)
#define OFF_MT  0                       // 512*16  rotated means
#define OFF_SH  (NNODES*16)             // 512*256 Shat = E^T Sigma E + eps I (symmetric)
#define OFF_P   (OFF_SH + NNODES*256)   // 512*256 P = (Shat)^-1 (symmetric)
#define OFF_LD  (OFF_P + NNODES*256)    // 512     2*sum log(sqrt(d_k)+eps)
#define OFF_KLS (OFF_LD + NNODES)       // 512     per-node kl_self
#define OFF_CE  (OFF_KLS + NNODES)      // 512     (unused)
#define OFF_AP  (OFF_CE + NNODES)       // 512     align tile partials
#define OFF_CEP (OFF_AP + NNODES)       // 512*32  ce chunk partial sums
#define WS_FLOATS (OFF_CEP + NNODES*CE_CH)

// wave-synchronous LDS visibility: whole-wave ds_write completes before
// subsequent ds_read (DS pipe is in-order per wave); just drain lgkm.
#define WAVE_SYNC() asm volatile("s_waitcnt lgkmcnt(0)" ::: "memory")

__device__ __forceinline__ void ld4(float* dst, const float4 v) {
  dst[0] = v.x; dst[1] = v.y; dst[2] = v.z; dst[3] = v.w;
}

__device__ __forceinline__ float dot16a(const float* a, const float* b) {
  float acc = 0.f;
  #pragma unroll
  for (int j = 0; j < 16; ++j) acc = fmaf(a[j], b[j], acc);
  return acc;
}

// In-register Gauss-Jordan inverse of 16x16 via shuffles.
// Lane (g=l>>4, c=l&15) holds aq[q] = A[4g+q][c]. Optional logdet (sum log pivots).
__device__ __forceinline__ void gj16(float aq[4], const int g, const int c, float* ldacc) {
  #pragma unroll
  for (int k = 0; k < 16; ++k) {
    float d    = __shfl(aq[k & 3], ((k >> 2) << 4) | k);
    float rowk = __shfl(aq[k & 3], ((k >> 2) << 4) | c);
    float ck[4];
    #pragma unroll
    for (int q = 0; q < 4; ++q) ck[q] = __shfl(aq[q], (g << 4) | k);
    if (ldacc) *ldacc += logf(d);
    float dinv = 1.f / d;
    #pragma unroll
    for (int q = 0; q < 4; ++q) {
      int r = 4*g + q;
      float vgen = fmaf(-ck[q] * dinv, rowk, aq[q]);
      aq[q] = (r == k) ? ((c == k) ? dinv : aq[q] * dinv)
                       : ((c == k) ? (-ck[q] * dinv) : vgen);
    }
  }
}

// Pivot-only Gaussian elimination: returns logdet-style sum over pivots.
// QUIRK=0: sum log(d). QUIRK=1: sum 2*log(sqrt(d)+EPS_AL) (ref Cholesky-diag quirk).
template<int QUIRK>
__device__ __forceinline__ float ge16_logdet(float aq[4], const int g, const int c) {
  float ld = 0.f;
  #pragma unroll
  for (int k = 0; k < 16; ++k) {
    float d    = __shfl(aq[k & 3], ((k >> 2) << 4) | k);
    float rowk = __shfl(aq[k & 3], ((k >> 2) << 4) | c);
    float ck[4];
    #pragma unroll
    for (int q = 0; q < 4; ++q) ck[q] = __shfl(aq[q], (g << 4) | k);
    ld += QUIRK ? 2.f * logf(sqrtf(d) + EPS_AL) : logf(d);
    float dinv = 1.f / d;
    #pragma unroll
    for (int q = 0; q < 4; ++q) {
      int r = 4*g + q;
      float upd = fmaf(-ck[q] * dinv, rowk, aq[q]);
      aq[q] = (r > k && c > k) ? upd : aq[q];
    }
  }
  return ld;
}

// ---------------- Kernel 1: wave-per-node prep, ZERO barriers ----------------
// 256 blocks x 4 waves; wave handles unit = bid*4+w; role=unit&1, node=unit>>1.
// role 0: E=expm(phi_mat); Shat=E^T Sigma E+eps; mt=E^T mu; P=inv(Shat)
// role 1: GJ(Sp)->Spinv+ldSp; GE(Sq)->ldSq; GE(Sg)->ld quirk; kl_self
__global__ __launch_bounds__(256) void prep_kernel(
    const float* __restrict__ mu, const float* __restrict__ Sigma,
    const float* __restrict__ phi, const float* __restrict__ mu_prior,
    const float* __restrict__ Sigma_prior, const float* __restrict__ gen,
    float* __restrict__ ws)
{
  __shared__ __align__(16) float wl[4][980];   // per-wave: COL(320) ROW(320) AUX(320), stride-20 cols
  const int tid = threadIdx.x;
  const int w = tid >> 6, l = tid & 63;
  const int g = l >> 4, c = l & 15;
  const int unit = blockIdx.x * 4 + w;
  const int role = unit & 1, node = unit >> 1;
  float* COLp = &wl[w][0];
  float* ROWp = &wl[w][320];
  float* AUXp = &wl[w][640];

  if (role == 0) {
    float phis[16];
    {
      const float4* p4 = (const float4*)(phi + node*16);
      ld4(phis, p4[0]); ld4(phis+4, p4[1]); ld4(phis+8, p4[2]); ld4(phis+12, p4[3]);
    }
    // X[4g+q][c] = 0.125*sum_a phi_a G[a][4g+q][c];  G[a][r][c] = -gen[a][c][r] (exact skew)
    float x[4] = {0.f, 0.f, 0.f, 0.f};
    #pragma unroll
    for (int aa = 0; aa < 16; ++aa) {
      float4 gq = *(const float4*)(gen + aa*256 + c*16 + 4*g);
      x[0] = fmaf(phis[aa], gq.x, x[0]);
      x[1] = fmaf(phis[aa], gq.y, x[1]);
      x[2] = fmaf(phis[aa], gq.z, x[2]);
      x[3] = fmaf(phis[aa], gq.w, x[3]);
    }
    #pragma unroll
    for (int q = 0; q < 4; ++q) x[q] *= -0.125f;

    // stash X rows, pull own 4 rows into registers
    #pragma unroll
    for (int q = 0; q < 4; ++q) ROWp[(4*g+q)*20 + c] = x[q];
    WAVE_SYNC();
    float Mrow[4][16];
    #pragma unroll
    for (int q = 0; q < 4; ++q)
      #pragma unroll
      for (int j4 = 0; j4 < 4; ++j4)
        ld4(&Mrow[q][4*j4], *(const float4*)&ROWp[(4*g+q)*20 + 4*j4]);

    // Horner order 8: t = I + X*0.125; t = I + X*t/k
    float t[4];
    #pragma unroll
    for (int q = 0; q < 4; ++q) t[q] = ((4*g+q) == c ? 1.f : 0.f) + x[q]*0.125f;
    for (int k = 7; k >= 1; --k) {
      *(float4*)&COLp[c*20 + 4*g] = make_float4(t[0], t[1], t[2], t[3]);
      WAVE_SYNC();
      float T[16];
      #pragma unroll
      for (int j4 = 0; j4 < 4; ++j4) ld4(&T[4*j4], *(const float4*)&COLp[c*20 + 4*j4]);
      #pragma unroll
      for (int q = 0; q < 4; ++q)
        t[q] = ((4*g+q) == c ? 1.f : 0.f) + dot16a(Mrow[q], T) / (float)k;
    }
    // 3 squarings -> E (orthogonal)
    for (int s = 0; s < 3; ++s) {
      *(float4*)&COLp[c*20 + 4*g] = make_float4(t[0], t[1], t[2], t[3]);
      #pragma unroll
      for (int q = 0; q < 4; ++q) ROWp[(4*g+q)*20 + c] = t[q];
      WAVE_SYNC();
      float T[16];
      #pragma unroll
      for (int j4 = 0; j4 < 4; ++j4) ld4(&T[4*j4], *(const float4*)&COLp[c*20 + 4*j4]);
      float nt[4];
      #pragma unroll
      for (int q = 0; q < 4; ++q) {
        float acc = 0.f;
        #pragma unroll
        for (int j4 = 0; j4 < 4; ++j4) {
          float4 rv = *(const float4*)&ROWp[(4*g+q)*20 + 4*j4];
          acc = fmaf(rv.x, T[4*j4+0], acc);
          acc = fmaf(rv.y, T[4*j4+1], acc);
          acc = fmaf(rv.z, T[4*j4+2], acc);
          acc = fmaf(rv.w, T[4*j4+3], acc);
        }
        nt[q] = acc;
      }
      #pragma unroll
      for (int q = 0; q < 4; ++q) t[q] = nt[q];
    }
    // finalize E in LDS (col-major) + own column in regs
    *(float4*)&COLp[c*20 + 4*g] = make_float4(t[0], t[1], t[2], t[3]);
    WAVE_SYNC();
    float Ecol[16];
    #pragma unroll
    for (int j4 = 0; j4 < 4; ++j4) ld4(&Ecol[4*j4], *(const float4*)&COLp[c*20 + 4*j4]);

    // W1 = Sigma * E (own entries)
    float w1q[4];
    #pragma unroll
    for (int q = 0; q < 4; ++q) {
      float S[16];
      const float4* s4 = (const float4*)(Sigma + node*256 + (4*g+q)*16);
      ld4(S, s4[0]); ld4(S+4, s4[1]); ld4(S+8, s4[2]); ld4(S+12, s4[3]);
      w1q[q] = dot16a(S, Ecol);
    }
    *(float4*)&AUXp[c*20 + 4*g] = make_float4(w1q[0], w1q[1], w1q[2], w1q[3]);
    WAVE_SYNC();
    float W1c[16];
    #pragma unroll
    for (int j4 = 0; j4 < 4; ++j4) ld4(&W1c[4*j4], *(const float4*)&AUXp[c*20 + 4*j4]);

    // Shat = E^T W1 + eps I  (symmetric -> store col-major quads)
    float sh[4];
    #pragma unroll
    for (int q = 0; q < 4; ++q) {
      float Er[16];
      #pragma unroll
      for (int j4 = 0; j4 < 4; ++j4) ld4(&Er[4*j4], *(const float4*)&COLp[(4*g+q)*20 + 4*j4]);
      sh[q] = dot16a(Er, W1c) + ((4*g+q) == c ? EPS_AL : 0.f);
    }
    *(float4*)(ws + OFF_SH + node*256 + c*16 + 4*g) = make_float4(sh[0], sh[1], sh[2], sh[3]);

    // mt = E^T mu
    {
      float muv[16];
      const float4* m4 = (const float4*)(mu + node*16);
      ld4(muv, m4[0]); ld4(muv+4, m4[1]); ld4(muv+8, m4[2]); ld4(muv+12, m4[3]);
      float mt = dot16a(Ecol, muv);
      if (g == 0) ws[OFF_MT + node*16 + c] = mt;
    }
    // P = inv(Shat)
    gj16(sh, g, c, (float*)nullptr);
    *(float4*)(ws + OFF_P + node*256 + c*16 + 4*g) = make_float4(sh[0], sh[1], sh[2], sh[3]);
  } else {
    // ---------- V_self + align logdet (all in registers) ----------
    float sp[4];
    {
      float4 v = *(const float4*)(Sigma_prior + node*256 + c*16 + 4*g);   // symmetric read
      sp[0] = v.x + ((4*g+0 == c) ? EPS_SELF : 0.f);
      sp[1] = v.y + ((4*g+1 == c) ? EPS_SELF : 0.f);
      sp[2] = v.z + ((4*g+2 == c) ? EPS_SELF : 0.f);
      sp[3] = v.w + ((4*g+3 == c) ? EPS_SELF : 0.f);
    }
    float ldSp = 0.f;
    gj16(sp, g, c, &ldSp);   // sp -> Spinv

    float dmur[4], dmuc;
    {
      float4 a = *(const float4*)(mu_prior + node*16 + 4*g);
      float4 b = *(const float4*)(mu + node*16 + 4*g);
      dmur[0] = a.x - b.x; dmur[1] = a.y - b.y; dmur[2] = a.z - b.z; dmur[3] = a.w - b.w;
      dmuc = mu_prior[node*16 + c] - mu[node*16 + c];
    }
    float val = 0.f;
    {
      float4 v = *(const float4*)(Sigma + node*256 + c*16 + 4*g);
      float s0 = v.x + ((4*g+0 == c) ? EPS_SELF : 0.f);
      float s1 = v.y + ((4*g+1 == c) ? EPS_SELF : 0.f);
      float s2 = v.z + ((4*g+2 == c) ? EPS_SELF : 0.f);
      float s3 = v.w + ((4*g+3 == c) ? EPS_SELF : 0.f);
      val = fmaf(sp[0], s0 + dmur[0]*dmuc, val);
      val = fmaf(sp[1], s1 + dmur[1]*dmuc, val);
      val = fmaf(sp[2], s2 + dmur[2]*dmuc, val);
      val = fmaf(sp[3], s3 + dmur[3]*dmuc, val);
    }
    #pragma unroll
    for (int o = 32; o; o >>= 1) val += __shfl_xor(val, o);

    float sq[4];
    {
      float4 v = *(const float4*)(Sigma + node*256 + c*16 + 4*g);
      sq[0] = v.x + ((4*g+0 == c) ? EPS_SELF : 0.f);
      sq[1] = v.y + ((4*g+1 == c) ? EPS_SELF : 0.f);
      sq[2] = v.z + ((4*g+2 == c) ? EPS_SELF : 0.f);
      sq[3] = v.w + ((4*g+3 == c) ? EPS_SELF : 0.f);
    }
    float ldSq = ge16_logdet<0>(sq, g, c);
    float sg[4];
    {
      float4 v = *(const float4*)(Sigma + node*256 + c*16 + 4*g);
      sg[0] = v.x + ((4*g+0 == c) ? EPS_AL : 0.f);
      sg[1] = v.y + ((4*g+1 == c) ? EPS_AL : 0.f);
      sg[2] = v.z + ((4*g+2 == c) ? EPS_AL : 0.f);
      sg[3] = v.w + ((4*g+3 == c) ? EPS_AL : 0.f);
    }
    float ldq = ge16_logdet<1>(sg, g, c);
    if (l == 0) {
      ws[OFF_KLS + node] = 0.5f * (val - 16.f + ldSp - ldSq);
      ws[OFF_LD + node]  = ldq;
    }
  }
}

// ---------------- Kernel 2: pairwise V_align (b128 LDS reads) ----------------
#define PSTR 260
__global__ __launch_bounds__(256) void align_kernel(
    const float* __restrict__ beta, const float* __restrict__ wsc, float* __restrict__ ws)
{
  __shared__ __align__(16) float ShI[16*PSTR];
  __shared__ __align__(16) float PJ[16*PSTR];
  __shared__ float mtI[256], mtJ[256], ldI[16], ldJ[16], red[4];
  const int tid = threadIdx.x;
  const int ti = tid & 15, tj = tid >> 4;
  const int bx = blockIdx.x, by = blockIdx.y, bz = blockIdx.z;
  const int nodeI0 = bz*256 + by*16, nodeJ0 = bz*256 + bx*16;

  for (int idx = tid; idx < 16*256; idx += 256) {
    int row = idx >> 8, col = idx & 255;
    ShI[row*PSTR + col] = wsc[OFF_SH + (nodeI0 + row)*256 + col];
    PJ [row*PSTR + col] = wsc[OFF_P  + (nodeJ0 + row)*256 + col];
  }
  mtI[tid] = wsc[OFF_MT + nodeI0*16 + tid];
  mtJ[tid] = wsc[OFF_MT + nodeJ0*16 + tid];
  if (tid < 16) { ldI[tid] = wsc[OFF_LD + nodeI0 + tid]; ldJ[tid] = wsc[OFF_LD + nodeJ0 + tid]; }
  __syncthreads();

  const float4* si4 = (const float4*)&ShI[ti*PSTR];
  const float4* pj4 = (const float4*)&PJ[tj*PSTR];
  float tr = 0.f;
  #pragma unroll 16
  for (int t = 0; t < 64; ++t) {
    float4 xv = si4[t], yv = pj4[t];
    tr = fmaf(xv.x, yv.x, tr);
    tr = fmaf(xv.y, yv.y, tr);
    tr = fmaf(xv.z, yv.z, tr);
    tr = fmaf(xv.w, yv.w, tr);
  }

  const float* pj = &PJ[tj*PSTR];
  float d[16];
  #pragma unroll
  for (int k = 0; k < 16; ++k) d[k] = mtJ[tj*16+k] - mtI[ti*16+k];
  float mah = 0.f;
  #pragma unroll
  for (int k = 0; k < 16; ++k) {
    float acc = 0.f;
    #pragma unroll
    for (int ll = 0; ll < 16; ++ll) acc = fmaf(pj[k*16+ll], d[ll], acc);
    mah = fmaf(d[k], acc, mah);
  }

  float kl = 0.5f * (tr + mah - 16.f + ldJ[tj] - ldI[ti]);
  kl = fmaxf(kl, 0.f);
  int gi = by*16 + ti, gj = bx*16 + tj;
  float contrib = (gi == gj) ? 0.f : kl * beta[bz*65536 + gi*256 + gj];
  // block reduce
  #pragma unroll
  for (int o = 32; o; o >>= 1) contrib += __shfl_down(contrib, o);
  __syncthreads();
  if ((tid & 63) == 0) red[tid >> 6] = contrib;
  __syncthreads();
  if (tid == 0) ws[OFF_AP + (bz*16 + by)*16 + bx] = red[0] + red[1] + red[2] + red[3];
}

// ---------------- Kernel 3: CE partial sums ----------------
#define DOT16(q0,q1,q2,q3,A) \
  fmaf(q0.x,A[0],fmaf(q0.y,A[1],fmaf(q0.z,A[2],fmaf(q0.w,A[3], \
  fmaf(q1.x,A[4],fmaf(q1.y,A[5],fmaf(q1.z,A[6],fmaf(q1.w,A[7], \
  fmaf(q2.x,A[8],fmaf(q2.y,A[9],fmaf(q2.z,A[10],fmaf(q2.w,A[11], \
  fmaf(q3.x,A[12],fmaf(q3.y,A[13],fmaf(q3.z,A[14],q3.w*A[15])))))))))))))))

__global__ __launch_bounds__(256) void ce1_kernel(
    const float* __restrict__ mu, const float* __restrict__ W,
    float* __restrict__ ws)
{
  __shared__ float mu_s[CE_ROWS*16];
  __shared__ float sred[CE_ROWS*256];
  const int tid = threadIdx.x;
  const int grp = blockIdx.x;
  const int ch  = blockIdx.y;
  const int row0 = grp * CE_ROWS;

  if (tid < CE_ROWS*16) mu_s[tid] = mu[row0*16 + tid];
  __syncthreads();

  float A[CE_ROWS][16];
  #pragma unroll
  for (int r = 0; r < CE_ROWS; ++r)
    #pragma unroll
    for (int k = 0; k < 16; ++k) A[r][k] = mu_s[r*16+k];

  float acc[CE_ROWS];
  #pragma unroll
  for (int r = 0; r < CE_ROWS; ++r) acc[r] = 0.f;

  const float4* W4 = (const float4*)W;
  const int v0 = ch * CE_CHUNK;
  for (int v = v0 + tid; v < v0 + CE_CHUNK; v += 256) {
    float4 q0 = W4[v*4+0], q1 = W4[v*4+1], q2 = W4[v*4+2], q3 = W4[v*4+3];
    #pragma unroll
    for (int r = 0; r < CE_ROWS; ++r) {
      float lg = DOT16(q0,q1,q2,q3,A[r]);
      acc[r] += __expf(lg);   // logits O(0.4): direct exp-sum fp32-safe
    }
  }

  #pragma unroll
  for (int r = 0; r < CE_ROWS; ++r) sred[r*256 + tid] = acc[r];
  __syncthreads();
  for (int h = 128; h > 0; h >>= 1) {
    if (tid < h) {
      #pragma unroll
      for (int r = 0; r < CE_ROWS; ++r) sred[r*256+tid] += sred[r*256+tid+h];
    }
    __syncthreads();
  }
  if (tid < CE_ROWS) ws[OFF_CEP + (row0 + tid)*CE_CH + ch] = sred[tid*256];
}

// ---------------- Kernel 4: CE finalize + deterministic reduce (1 block/batch) ----------------
__global__ __launch_bounds__(256) void final_kernel(
    const float* __restrict__ mu, const float* __restrict__ W,
    const int* __restrict__ targets, const float* __restrict__ ws,
    float* __restrict__ out)
{
  __shared__ double red[256];
  const int tid = threadIdx.x;
  const int b = blockIdx.x;
  const int row = b*256 + tid;
  float s = 0.f;
  #pragma unroll
  for (int c2 = 0; c2 < CE_CH; ++c2) s += ws[OFF_CEP + row*CE_CH + c2];
  int t = targets[row];
  float dt = 0.f;
  #pragma unroll
  for (int k = 0; k < 16; ++k) dt = fmaf(mu[row*16+k], W[t*16+k], dt);
  double ce = (double)logf(s) - (double)dt;
  red[tid] = (double)ws[OFF_KLS + row] + (double)ws[OFF_AP + row] + ce;
  __syncthreads();
  for (int h = 128; h > 0; h >>= 1) {
    if (tid < h) red[tid] += red[tid + h];
    __syncthreads();
  }
  if (tid == 0) out[b] = (float)red[0];
}

extern "C" void kernel_launch(void* const* d_in, const int* in_sizes, int n_in,
                              void* d_out, int out_size, void* d_ws, size_t ws_size,
                              hipStream_t stream) {
  const float* mu          = (const float*)d_in[0];
  const float* Sigma       = (const float*)d_in[1];
  const float* phi         = (const float*)d_in[2];
  const float* mu_prior    = (const float*)d_in[3];
  const float* Sigma_prior = (const float*)d_in[4];
  const float* beta        = (const float*)d_in[5];
  const float* W_out       = (const float*)d_in[6];
  const float* gen         = (const float*)d_in[7];
  const int*   targets     = (const int*)d_in[8];
  float* out = (float*)d_out;
  float* ws  = (float*)d_ws;
  if (ws_size < (size_t)WS_FLOATS * sizeof(float)) return;  // fail loudly

  prep_kernel<<<256, 256, 0, stream>>>(mu, Sigma, phi, mu_prior, Sigma_prior, gen, ws);
  dim3 ag(16, 16, NB);
  align_kernel<<<ag, 256, 0, stream>>>(beta, ws, ws);
  dim3 cg(NNODES/CE_ROWS, CE_CH);
  ce1_kernel<<<cg, 256, 0, stream>>>(mu, W_out, ws);
  final_kernel<<<NB, 256, 0, stream>>>(mu, W_out, targets, ws, out);
}